// Round 11
// baseline (125.646 us; speedup 1.0000x reference)
//
#include <hip/hip_runtime.h>

typedef short short8 __attribute__((ext_vector_type(8)));
typedef float f32x16 __attribute__((ext_vector_type(16)));

#define BN 4096
#define DD 128
#define MARGIN 0.3f
#define HP_INIT_BITS 0xBF800000u   /* -1.0f : "no positive seen" sentinel */
#define HN_INITF 1e30f

// round-to-nearest-even f32 -> bf16 bits (inputs finite; no NaN guard needed)
__device__ __forceinline__ unsigned short f2bf(float x) {
    unsigned u = __float_as_uint(x);
    return (unsigned short)((u + 0x7FFFu + ((u >> 16) & 1u)) >> 16);
}
__device__ __forceinline__ float bf2f(unsigned short b) {
    return __uint_as_float(((unsigned)b) << 16);
}
// 8 f32 -> packed hi(8 bf16) + lo(8 bf16 residual)
__device__ __forceinline__ void cvt8(float4 f0, float4 f1, int4& hi, int4& lo) {
    float x[8] = {f0.x, f0.y, f0.z, f0.w, f1.x, f1.y, f1.z, f1.w};
    unsigned hw[4], lw[4];
#pragma unroll
    for (int i = 0; i < 4; ++i) {
        unsigned short h0 = f2bf(x[2 * i]), h1 = f2bf(x[2 * i + 1]);
        hw[i] = (unsigned)h0 | ((unsigned)h1 << 16);
        lw[i] = (unsigned)f2bf(x[2 * i] - bf2f(h0)) |
                ((unsigned)f2bf(x[2 * i + 1] - bf2f(h1)) << 16);
    }
    hi = make_int4(hw[0], hw[1], hw[2], hw[3]);
    lo = make_int4(lw[0], lw[1], lw[2], lw[3]);
}

// ---------------- K1: sq-norms (+ optional hi/lo split; init state per path) ----------
template<bool SPLIT, bool PARTIALS>
__global__ __launch_bounds__(256) void k1_prep(
        const float* __restrict__ emb,
        unsigned* __restrict__ ehi, unsigned* __restrict__ elo,
        float* __restrict__ sqn, int* __restrict__ hp, int* __restrict__ hn,
        float* __restrict__ scal) {
    const int r = blockIdx.x * 4 + (threadIdx.x >> 6);
    const int l = threadIdx.x & 63;
    const float2 v = *reinterpret_cast<const float2*>(emb + (size_t)r * DD + l * 2);

    if constexpr (SPLIT) {
        unsigned short h0 = f2bf(v.x), h1 = f2bf(v.y);
        unsigned short l0 = f2bf(v.x - bf2f(h0)), l1 = f2bf(v.y - bf2f(h1));
        ehi[r * 64 + l] = (unsigned)h0 | ((unsigned)h1 << 16);
        elo[r * 64 + l] = (unsigned)l0 | ((unsigned)l1 << 16);
    }
    float s = v.x * v.x + v.y * v.y;
#pragma unroll
    for (int m = 1; m < 64; m <<= 1) s += __shfl_xor(s, m);
    if (l == 0) {
        sqn[r] = s;
        if constexpr (!PARTIALS) {
            hp[r] = (int)HP_INIT_BITS;
            hn[r] = __float_as_int(HN_INITF);
        }
    }
    if constexpr (PARTIALS) {
        if (blockIdx.x == 0 && threadIdx.x == 0) { scal[0] = 0.f; scal[1] = 0.f; }
    }
}

// ---------------- K2: 3-pass bf16-split MFMA Gram + fused masked row max/min on d2 ----
// grid 1024 linear (XCD-swizzled to (bx,by)), block 256 = 4 waves
// block tile 128x128; wave tile 64x64 (2x2 of 32x32)
// PRESPLIT: read precomputed ehi/elo. else: read f32 emb, split in-register.
// PARTIALS: plain coalesced float2 stores to part[64][4096]. else: global atomics.
template<bool PRESPLIT, bool PARTIALS>
__global__ __launch_bounds__(256) void k2_pairs(
        const unsigned short* __restrict__ ehi, const unsigned short* __restrict__ elo,
        const float* __restrict__ emb,
        const float* __restrict__ sqn, const int* __restrict__ labels,
        float2* __restrict__ part, int* __restrict__ hp, int* __restrict__ hn) {
    // 4 tiles [128 rows][64 k] bf16 (16 KB each): Ah | Al | Bh | Bl.  XOR-swizzled rows.
    __shared__ __align__(16) char lds[65536];

    // XCD-aware bijective swizzle (T1): 1024 % 8 == 0. Each XCD gets 4 contiguous
    // row-groups x all col-groups -> per-XCD L2 footprint ~2.25 MB < 4 MB.
    const int bid  = blockIdx.x;
    const int nbid = (bid & 7) * 128 + (bid >> 3);
    const int bx   = nbid & 31;    // col chunk
    const int by   = nbid >> 5;    // row chunk

    const int t    = threadIdx.x;
    const int srow = t >> 3;          // staging: row mod 32
    const int ss   = t & 7;           // staging: 16B-(bf16)/32B-(f32) slot = 8 elems
    const int w    = t >> 6;          // wave 0..3
    const int l    = t & 63;
    const int l31  = l & 31;
    const int kg   = l >> 5;          // k-group half
    const int Rw   = (w >> 1) * 64;   // wave row range in block
    const int Cw   = (w & 1) * 64;    // wave col range in block
    const int rowBase = by * 128;
    const int colBase = bx * 128;

    f32x16 acc[2][2];
#pragma unroll
    for (int a = 0; a < 2; ++a)
#pragma unroll
        for (int b = 0; b < 2; ++b)
#pragma unroll
            for (int i = 0; i < 16; ++i) acc[a][b][i] = 0.0f;

    int4 stg[16];   // 256B/thread either way (presplit: 2 arrays x 16B; f32: 1 array x 32B)

    auto STAGE_LOAD = [&](int p) {   // T14 issue phase: global -> regs
        if constexpr (PRESPLIT) {
#pragma unroll
            for (int g = 0; g < 4; ++g)
#pragma unroll
                for (int q = 0; q < 4; ++q) {
                    const int row = q * 32 + srow;
                    const unsigned short* src = (g & 1) ? elo : ehi;
                    const int rb = (g < 2) ? rowBase : colBase;
                    stg[g * 4 + q] = *reinterpret_cast<const int4*>(
                        src + (size_t)(rb + row) * DD + p * 64 + ss * 8);
                }
        } else {
#pragma unroll
            for (int ga = 0; ga < 2; ++ga)
#pragma unroll
                for (int q = 0; q < 4; ++q)
#pragma unroll
                    for (int h = 0; h < 2; ++h) {
                        const int row = q * 32 + srow;
                        const int rb = ga ? colBase : rowBase;
                        stg[(ga * 4 + q) * 2 + h] = *reinterpret_cast<const int4*>(
                            emb + (size_t)(rb + row) * DD + p * 64 + ss * 8 + h * 4);
                    }
        }
    };
    auto STAGE_WRITE = [&]() {       // T14 write phase: regs -> swizzled LDS (+split if f32)
        if constexpr (PRESPLIT) {
#pragma unroll
            for (int g = 0; g < 4; ++g)
#pragma unroll
                for (int q = 0; q < 4; ++q) {
                    const int row = q * 32 + srow;
                    *reinterpret_cast<int4*>(lds + g * 16384 + row * 128 +
                                             ((ss ^ (row & 7)) << 4)) = stg[g * 4 + q];
                }
        } else {
#pragma unroll
            for (int ga = 0; ga < 2; ++ga)
#pragma unroll
                for (int q = 0; q < 4; ++q) {
                    const int row = q * 32 + srow;
                    int4 hi, lo;
                    cvt8(__builtin_bit_cast(float4, stg[(ga * 4 + q) * 2]),
                         __builtin_bit_cast(float4, stg[(ga * 4 + q) * 2 + 1]), hi, lo);
                    const int off = row * 128 + ((ss ^ (row & 7)) << 4);
                    *reinterpret_cast<int4*>(lds + (ga * 2) * 16384 + off)     = hi;
                    *reinterpret_cast<int4*>(lds + (ga * 2 + 1) * 16384 + off) = lo;
                }
        }
    };
    auto CHUNKS = [&]() {   // 4 chunks of K=16 over the staged 64-k phase; no barriers inside
#pragma unroll
        for (int c = 0; c < 4; ++c) {
            short8 ah[2], al[2], bh[2], bl[2];
#pragma unroll
            for (int a = 0; a < 2; ++a) {
                const int row = Rw + a * 32 + l31;
                const int off = row * 128 + (((c * 2 + kg) ^ (row & 7)) << 4);
                ah[a] = *reinterpret_cast<const short8*>(lds + off);
                al[a] = *reinterpret_cast<const short8*>(lds + 16384 + off);
            }
#pragma unroll
            for (int b = 0; b < 2; ++b) {
                const int row = Cw + b * 32 + l31;
                const int off = row * 128 + (((c * 2 + kg) ^ (row & 7)) << 4);
                bh[b] = *reinterpret_cast<const short8*>(lds + 32768 + off);
                bl[b] = *reinterpret_cast<const short8*>(lds + 49152 + off);
            }
#pragma unroll
            for (int a = 0; a < 2; ++a)
#pragma unroll
                for (int b = 0; b < 2; ++b) {
                    acc[a][b] = __builtin_amdgcn_mfma_f32_32x32x16_bf16(ah[a], bh[b], acc[a][b], 0, 0, 0);
                    acc[a][b] = __builtin_amdgcn_mfma_f32_32x32x16_bf16(ah[a], bl[b], acc[a][b], 0, 0, 0);
                    acc[a][b] = __builtin_amdgcn_mfma_f32_32x32x16_bf16(al[a], bh[b], acc[a][b], 0, 0, 0);
                }
        }
    };

    STAGE_LOAD(0);
    STAGE_WRITE();
    __syncthreads();        // phase-0 tiles visible
    STAGE_LOAD(1);          // issue phase-1 globals EARLY: latency hides under CHUNKS (T14)
    CHUNKS();               // k 0..63
    __syncthreads();        // everyone done READING phase-0 tiles
    STAGE_WRITE();
    __syncthreads();        // phase-1 tiles visible
    CHUNKS();               // k 64..127
    __syncthreads();        // tiles dead -> LDS becomes per-wave scratch

    // ---- epilogue: d2 + masks + per-row max/min, LDS-transpose reduce ----
    float sqJ[2]; int labJ[2], jg[2];
#pragma unroll
    for (int b = 0; b < 2; ++b) {
        jg[b]   = colBase + Cw + b * 32 + l31;
        sqJ[b]  = sqn[jg[b]];
        labJ[b] = labels[jg[b]];
    }
    char* scr = lds + w * 16384;   // per-wave [64 rows][32 cols] of {hp,hn} f32 pairs
#pragma unroll
    for (int a = 0; a < 2; ++a) {
#pragma unroll
        for (int rr = 0; rr < 16; ++rr) {
            const int crow = (rr & 3) + 8 * (rr >> 2) + 4 * kg;   // HW C/D row mapping (m74/m101)
            const int ig = rowBase + Rw + a * 32 + crow;
            const float sI = sqn[ig];
            const int   lI = labels[ig];
            float hpv = -1.0f, hnv = HN_INITF;
#pragma unroll
            for (int b = 0; b < 2; ++b) {
                const float v  = acc[a][b][rr];
                const float d2 = fmaf(-2.0f, v, sI + sqJ[b]);
                const bool same = (lI == labJ[b]);
                const float pc = (same && ig != jg[b]) ? fmaxf(d2, 0.0f) : -1.0f;
                const float nc = same ? HN_INITF : d2;
                hpv = fmaxf(hpv, pc);
                hnv = fminf(hnv, nc);
            }
            float2* slot = reinterpret_cast<float2*>(scr + ((a * 32 + crow) * 32 + l31) * 8);
            *slot = make_float2(hpv, hnv);
        }
    }
    // same-wave LDS ordering: compiler inserts lgkmcnt before dependent reads
    float hpr = -1.0f, hnr = HN_INITF;
#pragma unroll
    for (int c = 0; c < 32; ++c) {
        const int cc = (c + l31) & 31;   // rotated read -> conflict-free
        const float2 pv = *reinterpret_cast<const float2*>(scr + l * 256 + cc * 8);
        hpr = fmaxf(hpr, pv.x);
        hnr = fminf(hnr, pv.y);
    }
    const int ig = rowBase + Rw + l;
    if constexpr (PARTIALS) {
        // plain coalesced store: slice = bx*2 + column-half of this wave
        part[((bx * 2 + (w & 1)) << 12) + ig] = make_float2(hpr, hnr);
    } else {
        atomicMax(hp + ig, __float_as_int(hpr));   // >=0 or -1.0 sentinel: int-monotone
        atomicMin(hn + ig, __float_as_int(hnr));   // positives int-monotone; negatives
                                                   // all clamp identically downstream
    }
}

// ---------------- K3 (partials): reduce 64 slices -> per-row loss -> block sums ----
__global__ __launch_bounds__(128) void k3_part(
        const float2* __restrict__ part, float* __restrict__ scal) {
    __shared__ float bS[2], bC[2];
    const int r = blockIdx.x * 128 + threadIdx.x;   // lanes = consecutive rows: coalesced
    float hp_r = -1.0f, hn_r = HN_INITF;
#pragma unroll 8
    for (int cx = 0; cx < 64; ++cx) {
        const float2 v = part[(cx << 12) + r];
        hp_r = fmaxf(hp_r, v.x);
        hn_r = fminf(hn_r, v.y);
    }
    float sum = 0.f, cnt = 0.f;
    if (hp_r >= 0.f && hn_r < 1e29f) {
        const float dp = sqrtf(fmaxf(hp_r, 1e-12f));
        const float dn = sqrtf(fmaxf(hn_r, 1e-12f));
        sum = fmaxf(dp - dn + MARGIN, 0.f);
        cnt = 1.f;
    }
#pragma unroll
    for (int off = 32; off > 0; off >>= 1) {
        sum += __shfl_down(sum, off);
        cnt += __shfl_down(cnt, off);
    }
    const int wv = threadIdx.x >> 6;
    if ((threadIdx.x & 63) == 0) { bS[wv] = sum; bC[wv] = cnt; }
    __syncthreads();
    if (threadIdx.x == 0) {
        atomicAdd(scal + 0, bS[0] + bS[1]);
        atomicAdd(scal + 1, bC[0] + bC[1]);
    }
}

// ---------------- K4: final division ----------------
__global__ __launch_bounds__(64) void k4_final(
        const float* __restrict__ scal, float* __restrict__ out) {
    if (threadIdx.x == 0) out[0] = scal[0] / fmaxf(scal[1], 1.f);
}

// ---------------- K3 (atomic fallback, path C): per-row loss + mean ----------------
__global__ __launch_bounds__(1024) void k3_loss(
        const int* __restrict__ hp, const int* __restrict__ hn, float* __restrict__ out) {
    __shared__ float sS[16], sC[16];
    const int t = threadIdx.x;
    float sum = 0.f, cnt = 0.f;
#pragma unroll
    for (int q = 0; q < BN / 1024; ++q) {
        const int r = t + 1024 * q;
        const int pb = hp[r];
        const float n2 = __int_as_float(hn[r]);
        if (pb != (int)HP_INIT_BITS && n2 < 1e29f) {
            const float dp = sqrtf(fmaxf(__int_as_float(pb), 1e-12f));
            const float dn = sqrtf(fmaxf(n2, 1e-12f));
            sum += fmaxf(dp - dn + MARGIN, 0.f);
            cnt += 1.f;
        }
    }
#pragma unroll
    for (int off = 32; off > 0; off >>= 1) {
        sum += __shfl_down(sum, off);
        cnt += __shfl_down(cnt, off);
    }
    const int wv = t >> 6;
    if ((t & 63) == 0) { sS[wv] = sum; sC[wv] = cnt; }
    __syncthreads();
    if (t == 0) {
        float S = 0.f, C = 0.f;
#pragma unroll
        for (int q = 0; q < 16; ++q) { S += sS[q]; C += sC[q]; }
        out[0] = S / fmaxf(C, 1.f);
    }
}

extern "C" void kernel_launch(void* const* d_in, const int* in_sizes, int n_in,
                              void* d_out, int out_size, void* d_ws, size_t ws_size,
                              hipStream_t stream) {
    const float* emb    = (const float*)d_in[0];
    const int*   labels = (const int*)d_in[1];
    char* ws = (char*)d_ws;
    float* out = (float*)d_out;

    const size_t PART_BYTES  = (size_t)64 * BN * 8;            // 2 MB  [64 slices][4096] f2
    const size_t SQN_OFF     = PART_BYTES;                     // 16 KB
    const size_t SCAL_OFF    = PART_BYTES + 16384;             // 256 B
    const size_t SPLIT_OFF   = SCAL_OFF + 256;                 // 2 x 1 MB
    const size_t NEED_PART   = SPLIT_OFF;
    const size_t NEED_SPLIT  = SPLIT_OFF + ((size_t)2u << 20);

    if (ws_size >= NEED_PART) {
        // Paths A/B: partial stores, no global atomics on the hot path
        float2* part = (float2*)ws;
        float*  sqn  = (float*)(ws + SQN_OFF);
        float*  scal = (float*)(ws + SCAL_OFF);
        const bool presplit = ws_size >= NEED_SPLIT;
        unsigned* ehi = (unsigned*)(ws + SPLIT_OFF);
        unsigned* elo = (unsigned*)(ws + SPLIT_OFF + (1u << 20));

        if (presplit) {
            k1_prep<true, true><<<BN / 4, 256, 0, stream>>>(emb, ehi, elo, sqn,
                                                            nullptr, nullptr, scal);
            k2_pairs<true, true><<<1024, 256, 0, stream>>>(
                (const unsigned short*)ehi, (const unsigned short*)elo,
                emb, sqn, labels, part, nullptr, nullptr);
        } else {
            k1_prep<false, true><<<BN / 4, 256, 0, stream>>>(emb, nullptr, nullptr, sqn,
                                                             nullptr, nullptr, scal);
            k2_pairs<false, true><<<1024, 256, 0, stream>>>(
                nullptr, nullptr, emb, sqn, labels, part, nullptr, nullptr);
        }
        k3_part<<<BN / 128, 128, 0, stream>>>(part, scal);
        k4_final<<<1, 64, 0, stream>>>(scal, out);
    } else {
        // Path C: proven atomic fallback (48 KB workspace)
        float* sqn = (float*)ws;
        int*   hp  = (int*)(ws + 16384);
        int*   hn  = (int*)(ws + 32768);
        k1_prep<false, false><<<BN / 4, 256, 0, stream>>>(emb, nullptr, nullptr, sqn,
                                                          hp, hn, nullptr);
        k2_pairs<false, false><<<1024, 256, 0, stream>>>(
            nullptr, nullptr, emb, sqn, labels, nullptr, hp, hn);
        k3_loss<<<1, 1024, 0, stream>>>(hp, hn, out);
    }
}

// Round 13
// 91.438 us; speedup vs baseline: 1.3741x; 1.3741x over previous
//
#include <hip/hip_runtime.h>

typedef short short8 __attribute__((ext_vector_type(8)));
typedef float f32x16 __attribute__((ext_vector_type(16)));

#define BN 4096
#define DD 128
#define MARGIN 0.3f
#define HN_INITF 1e30f

// round-to-nearest-even f32 -> bf16 bits (inputs finite)
__device__ __forceinline__ unsigned short f2bf(float x) {
    unsigned u = __float_as_uint(x);
    return (unsigned short)((u + 0x7FFFu + ((u >> 16) & 1u)) >> 16);
}
__device__ __forceinline__ float bf2f(unsigned short b) {
    return __uint_as_float(((unsigned)b) << 16);
}
// 8 f32 -> packed hi(8 bf16) + lo(8 bf16 residual)
__device__ __forceinline__ void cvt8(float4 f0, float4 f1, int4& hi, int4& lo) {
    float x[8] = {f0.x, f0.y, f0.z, f0.w, f1.x, f1.y, f1.z, f1.w};
    unsigned hw[4], lw[4];
#pragma unroll
    for (int i = 0; i < 4; ++i) {
        unsigned short h0 = f2bf(x[2 * i]), h1 = f2bf(x[2 * i + 1]);
        hw[i] = (unsigned)h0 | ((unsigned)h1 << 16);
        lw[i] = (unsigned)f2bf(x[2 * i] - bf2f(h0)) |
                ((unsigned)f2bf(x[2 * i + 1] - bf2f(h1)) << 16);
    }
    hi = make_int4(hw[0], hw[1], hw[2], hw[3]);
    lo = make_int4(lw[0], lw[1], lw[2], lw[3]);
}

// ---------------- K1: sq-norms + hp/hn init (every launch) ----------------
__global__ __launch_bounds__(256) void k1_prep(
        const float* __restrict__ emb, float* __restrict__ sqn,
        int* __restrict__ hp, int* __restrict__ hn) {
    const int r = blockIdx.x * 4 + (threadIdx.x >> 6);
    const int l = threadIdx.x & 63;
    const float2 v = *reinterpret_cast<const float2*>(emb + (size_t)r * DD + l * 2);
    float s = v.x * v.x + v.y * v.y;
#pragma unroll
    for (int m = 1; m < 64; m <<= 1) s += __shfl_xor(s, m);
    if (l == 0) {
        sqn[r] = s;
        hp[r] = __float_as_int(-1.0f);       // "no positive" sentinel
        hn[r] = __float_as_int(HN_INITF);
    }
}

// ---------------- K2: col-tile-looping MFMA Gram + fused masked row max/min ----------
// grid 512 (32 by x 16 bx, XCD-swizzled); block = 4 waves; 128x128 tile per inner step;
// each block loops 2 col-tiles, accumulating hp/hn in registers; LDS fold at end;
// UNCONDITIONAL device-scope atomics (131K pairs) -- correct under XCD L2 non-coherence
// across graph replays (pre-checked variant FAILED: stale cross-launch L2 lines).
__global__ __launch_bounds__(256) void k2_pairs(
        const float* __restrict__ emb,
        const float* __restrict__ sqn, const int* __restrict__ labels,
        int* __restrict__ hp, int* __restrict__ hn) {
    constexpr int NCS = 16, TPT = 2;
    __shared__ __align__(16) char lds[65536];   // Ah|Al|Bh|Bl [128][64] bf16 tiles

    // XCD-aware bijective swizzle: 512 % 8 == 0.
    const int bid  = blockIdx.x;
    const int nbid = (bid & 7) * 64 + (bid >> 3);
    const int by   = nbid / NCS;
    const int bx   = nbid % NCS;
    const int rowBase = by * 128;

    const int t    = threadIdx.x;
    const int srow = t >> 3;          // staging row mod 32
    const int ss   = t & 7;           // staging 8-elem slot
    const int w    = t >> 6;          // wave 0..3
    const int l    = t & 63;
    const int l31  = l & 31;
    const int kg   = l >> 5;
    const int Rw   = (w >> 1) * 64;   // wave rows in block
    const int Cw   = (w & 1) * 64;    // wave cols in tile

    f32x16 acc[2][2];
#pragma unroll
    for (int a = 0; a < 2; ++a)
#pragma unroll
        for (int b = 0; b < 2; ++b)
#pragma unroll
            for (int i = 0; i < 16; ++i) acc[a][b][i] = 0.0f;

    float hpv[2][16], hnv[2][16];     // running per-(a,rr) across tiles (static idx)
#pragma unroll
    for (int a = 0; a < 2; ++a)
#pragma unroll
        for (int rr = 0; rr < 16; ++rr) { hpv[a][rr] = -1.0f; hnv[a][rr] = HN_INITF; }

    int4 stg[16];
    int colBase = 0;

    auto STAGE_LOAD = [&](int p) {    // global f32 -> regs (T14 issue phase)
#pragma unroll
        for (int ga = 0; ga < 2; ++ga)
#pragma unroll
            for (int q = 0; q < 4; ++q)
#pragma unroll
                for (int h = 0; h < 2; ++h) {
                    const int row = q * 32 + srow;
                    const int rb = ga ? colBase : rowBase;
                    stg[(ga * 4 + q) * 2 + h] = *reinterpret_cast<const int4*>(
                        emb + (size_t)(rb + row) * DD + p * 64 + ss * 8 + h * 4);
                }
    };
    auto STAGE_WRITE = [&]() {        // split hi/lo + swizzled LDS write
#pragma unroll
        for (int ga = 0; ga < 2; ++ga)
#pragma unroll
            for (int q = 0; q < 4; ++q) {
                const int row = q * 32 + srow;
                int4 hi, lo;
                cvt8(__builtin_bit_cast(float4, stg[(ga * 4 + q) * 2]),
                     __builtin_bit_cast(float4, stg[(ga * 4 + q) * 2 + 1]), hi, lo);
                const int off = row * 128 + ((ss ^ (row & 7)) << 4);
                *reinterpret_cast<int4*>(lds + (ga * 2) * 16384 + off)     = hi;
                *reinterpret_cast<int4*>(lds + (ga * 2 + 1) * 16384 + off) = lo;
            }
    };
    auto CHUNKS = [&]() {             // 4 x K=16 over staged 64-k phase (3-pass hi/lo)
#pragma unroll
        for (int c = 0; c < 4; ++c) {
            short8 ah[2], al[2], bh[2], bl[2];
#pragma unroll
            for (int a = 0; a < 2; ++a) {
                const int row = Rw + a * 32 + l31;
                const int off = row * 128 + (((c * 2 + kg) ^ (row & 7)) << 4);
                ah[a] = *reinterpret_cast<const short8*>(lds + off);
                al[a] = *reinterpret_cast<const short8*>(lds + 16384 + off);
            }
#pragma unroll
            for (int b = 0; b < 2; ++b) {
                const int row = Cw + b * 32 + l31;
                const int off = row * 128 + (((c * 2 + kg) ^ (row & 7)) << 4);
                bh[b] = *reinterpret_cast<const short8*>(lds + 32768 + off);
                bl[b] = *reinterpret_cast<const short8*>(lds + 49152 + off);
            }
#pragma unroll
            for (int a = 0; a < 2; ++a)
#pragma unroll
                for (int b = 0; b < 2; ++b) {
                    acc[a][b] = __builtin_amdgcn_mfma_f32_32x32x16_bf16(ah[a], bh[b], acc[a][b], 0, 0, 0);
                    acc[a][b] = __builtin_amdgcn_mfma_f32_32x32x16_bf16(ah[a], bl[b], acc[a][b], 0, 0, 0);
                    acc[a][b] = __builtin_amdgcn_mfma_f32_32x32x16_bf16(al[a], bh[b], acc[a][b], 0, 0, 0);
                }
        }
    };

    for (int ct = 0; ct < TPT; ++ct) {
        colBase = (bx * TPT + ct) * 128;
        STAGE_LOAD(0);          // regs only; safe before barrier
        __syncthreads();        // all waves done READING previous tile's LDS
        STAGE_WRITE();
        __syncthreads();        // phase-0 tiles visible
        STAGE_LOAD(1);          // issue phase-1 globals early (T14)
        CHUNKS();               // k 0..63
        __syncthreads();
        STAGE_WRITE();
        __syncthreads();        // phase-1 tiles visible
        CHUNKS();               // k 64..127

        // fused epilogue-accumulate (regs + cached scalar loads only)
        float sqJ[2]; int labJ[2], jg[2];
#pragma unroll
        for (int b = 0; b < 2; ++b) {
            jg[b]   = colBase + Cw + b * 32 + l31;
            sqJ[b]  = sqn[jg[b]];
            labJ[b] = labels[jg[b]];
        }
#pragma unroll
        for (int a = 0; a < 2; ++a)
#pragma unroll
            for (int rr = 0; rr < 16; ++rr) {
                const int crow = (rr & 3) + 8 * (rr >> 2) + 4 * kg;  // C/D map (m74/m101)
                const int ig = rowBase + Rw + a * 32 + crow;
                const float sI = sqn[ig];
                const int   lI = labels[ig];
#pragma unroll
                for (int b = 0; b < 2; ++b) {
                    const float v  = acc[a][b][rr];
                    const float d2 = fmaf(-2.0f, v, sI + sqJ[b]);
                    const bool same = (lI == labJ[b]);
                    const float pc = (same && ig != jg[b]) ? fmaxf(d2, 0.0f) : -1.0f;
                    const float nc = same ? HN_INITF : d2;
                    hpv[a][rr] = fmaxf(hpv[a][rr], pc);
                    hnv[a][rr] = fminf(hnv[a][rr], nc);
                }
            }
#pragma unroll
        for (int a = 0; a < 2; ++a)
#pragma unroll
            for (int b = 0; b < 2; ++b)
#pragma unroll
                for (int i = 0; i < 16; ++i) acc[a][b][i] = 0.0f;
    }

    __syncthreads();            // all tiles done -> LDS becomes scratch
    // per-wave [64 rows][32 cols] fold
    char* scr = lds + w * 16384;
#pragma unroll
    for (int a = 0; a < 2; ++a)
#pragma unroll
        for (int rr = 0; rr < 16; ++rr) {
            const int crow = (rr & 3) + 8 * (rr >> 2) + 4 * kg;
            *reinterpret_cast<float2*>(scr + ((a * 32 + crow) * 32 + l31) * 8) =
                make_float2(hpv[a][rr], hnv[a][rr]);
        }
    float hpr = -1.0f, hnr = HN_INITF;   // same-wave LDS ordering via lgkmcnt
#pragma unroll
    for (int c = 0; c < 32; ++c) {
        const int cc = (c + l31) & 31;   // rotated read -> conflict-free
        const float2 pv = *reinterpret_cast<const float2*>(scr + l * 256 + cc * 8);
        hpr = fmaxf(hpr, pv.x);
        hnr = fminf(hnr, pv.y);
    }
    // cross-wave column-half fold: waves {0,1} share rows 0..63, {2,3} rows 64..127
    __syncthreads();
    float2* xw = reinterpret_cast<float2*>(lds);   // [4][64]
    xw[w * 64 + l] = make_float2(hpr, hnr);
    __syncthreads();
    if (t < 128) {
        const int r  = t;
        const int wa = (r < 64) ? 0 : 2;
        const int li = r & 63;
        const float2 u0 = xw[wa * 64 + li];
        const float2 u1 = xw[(wa + 1) * 64 + li];
        const float fp = fmaxf(u0.x, u1.x);
        const float fn = fminf(u0.y, u1.y);
        const int gr = rowBase + r;
        // UNCONDITIONAL device-scope atomics: correct under stale cross-launch
        // L2 lines (normal-load pre-check is NOT -- measured Round 12 failure).
        atomicMax(hp + gr, __float_as_int(fp));
        atomicMin(hn + gr, __float_as_int(fn));
    }
}

// ---------------- K3: per-row loss + mean over valid ----------------
__global__ __launch_bounds__(1024) void k3_loss(
        const int* __restrict__ hp, const int* __restrict__ hn, float* __restrict__ out) {
    __shared__ float sS[16], sC[16];
    const int t = threadIdx.x;
    float sum = 0.f, cnt = 0.f;
#pragma unroll
    for (int q = 0; q < BN / 1024; ++q) {
        const int r = t + 1024 * q;
        const float p2 = __int_as_float(hp[r]);
        const float n2 = __int_as_float(hn[r]);
        if (p2 >= 0.f && n2 < 1e29f) {
            const float dp = sqrtf(fmaxf(p2, 1e-12f));
            const float dn = sqrtf(fmaxf(n2, 1e-12f));
            sum += fmaxf(dp - dn + MARGIN, 0.f);
            cnt += 1.f;
        }
    }
#pragma unroll
    for (int off = 32; off > 0; off >>= 1) {
        sum += __shfl_down(sum, off);
        cnt += __shfl_down(cnt, off);
    }
    const int wv = t >> 6;
    if ((t & 63) == 0) { sS[wv] = sum; sC[wv] = cnt; }
    __syncthreads();
    if (t == 0) {
        float S = 0.f, C = 0.f;
#pragma unroll
        for (int q = 0; q < 16; ++q) { S += sS[q]; C += sC[q]; }
        out[0] = S / fmaxf(C, 1.f);
    }
}

extern "C" void kernel_launch(void* const* d_in, const int* in_sizes, int n_in,
                              void* d_out, int out_size, void* d_ws, size_t ws_size,
                              hipStream_t stream) {
    const float* emb    = (const float*)d_in[0];
    const int*   labels = (const int*)d_in[1];
    char* ws = (char*)d_ws;
    float* out = (float*)d_out;

    // 48 KB footprint (proven safe: Rounds 7/11 ran at these offsets)
    float* sqn = (float*)ws;
    int*   hp  = (int*)(ws + 16384);
    int*   hn  = (int*)(ws + 32768);

    k1_prep<<<BN / 4, 256, 0, stream>>>(emb, sqn, hp, hn);
    k2_pairs<<<512, 256, 0, stream>>>(emb, sqn, labels, hp, hn);
    k3_loss<<<1, 1024, 0, stream>>>(hp, hn, out);
}

// Round 14
// 79.376 us; speedup vs baseline: 1.5829x; 1.1520x over previous
//
#include <hip/hip_runtime.h>

typedef _Float16 half8 __attribute__((ext_vector_type(8)));
typedef float f32x16 __attribute__((ext_vector_type(16)));

#define BN 4096
#define DD 128
#define MARGIN 0.3f
#define HN_INITF 1e30f

// 8 f32 -> 8 fp16 (compiler emits v_cvt_f16_f32 / cvt_pk; do NOT hand-bit-twiddle, m240)
__device__ __forceinline__ int4 cvt8h(float4 f0, float4 f1) {
    half8 h;
    h[0] = (_Float16)f0.x; h[1] = (_Float16)f0.y;
    h[2] = (_Float16)f0.z; h[3] = (_Float16)f0.w;
    h[4] = (_Float16)f1.x; h[5] = (_Float16)f1.y;
    h[6] = (_Float16)f1.z; h[7] = (_Float16)f1.w;
    return __builtin_bit_cast(int4, h);
}

// ---------------- K1: sq-norms (f32 exact) + hp/hn init (every launch) ----------------
__global__ __launch_bounds__(256) void k1_prep(
        const float* __restrict__ emb, float* __restrict__ sqn,
        int* __restrict__ hp, int* __restrict__ hn) {
    const int r = blockIdx.x * 4 + (threadIdx.x >> 6);
    const int l = threadIdx.x & 63;
    const float2 v = *reinterpret_cast<const float2*>(emb + (size_t)r * DD + l * 2);
    float s = v.x * v.x + v.y * v.y;
#pragma unroll
    for (int m = 1; m < 64; m <<= 1) s += __shfl_xor(s, m);
    if (l == 0) {
        sqn[r] = s;
        hp[r] = __float_as_int(-1.0f);       // "no positive" sentinel
        hn[r] = __float_as_int(HN_INITF);
    }
}

// ---------------- K2: single-pass fp16 MFMA Gram + fused masked row max/min ----------
// grid 512 (32 by x 16 bx, XCD-swizzled); block = 4 waves; 128x128 tile per step;
// 2 col-tiles per block, hp/hn accumulated in registers; LDS fold; unconditional
// device-scope atomics (R12 lesson: no load pre-check -- stale cross-launch L2).
// fp16 1-pass accuracy: dist err ~7e-4, final bias ~0.005 << 9.2e-2 threshold.
__global__ __launch_bounds__(256, 2) void k2_pairs(
        const float* __restrict__ emb,
        const float* __restrict__ sqn, const int* __restrict__ labels,
        int* __restrict__ hp, int* __restrict__ hn) {
    constexpr int NCS = 16, TPT = 2;
    // A fp16 tile [128][64] @0 (16 KB), B @16384 (16 KB); [32K,64K) + all = fold scratch
    __shared__ __align__(16) char lds[65536];

    // XCD-aware bijective swizzle: 512 % 8 == 0.
    const int bid  = blockIdx.x;
    const int nbid = (bid & 7) * 64 + (bid >> 3);
    const int by   = nbid / NCS;
    const int bx   = nbid % NCS;
    const int rowBase = by * 128;

    const int t    = threadIdx.x;
    const int srow = t >> 3;          // staging row mod 32
    const int ss   = t & 7;           // staging 8-elem slot
    const int w    = t >> 6;          // wave 0..3
    const int l    = t & 63;
    const int l31  = l & 31;
    const int kg   = l >> 5;
    const int Rw   = (w >> 1) * 64;   // wave rows in block
    const int Cw   = (w & 1) * 64;    // wave cols in tile

    f32x16 acc[2][2];
#pragma unroll
    for (int a = 0; a < 2; ++a)
#pragma unroll
        for (int b = 0; b < 2; ++b)
#pragma unroll
            for (int i = 0; i < 16; ++i) acc[a][b][i] = 0.0f;

    float hpv[2][16], hnv[2][16];     // running per-(a,rr) across tiles (static idx)
#pragma unroll
    for (int a = 0; a < 2; ++a)
#pragma unroll
        for (int rr = 0; rr < 16; ++rr) { hpv[a][rr] = -1.0f; hnv[a][rr] = HN_INITF; }

    int4 stg[16];
    int colBase = 0;

    auto STAGE_LOAD = [&](int p) {    // global f32 -> regs (T14 issue phase)
#pragma unroll
        for (int ga = 0; ga < 2; ++ga)
#pragma unroll
            for (int q = 0; q < 4; ++q)
#pragma unroll
                for (int h = 0; h < 2; ++h) {
                    const int row = q * 32 + srow;
                    const int rb = ga ? colBase : rowBase;
                    stg[(ga * 4 + q) * 2 + h] = *reinterpret_cast<const int4*>(
                        emb + (size_t)(rb + row) * DD + p * 64 + ss * 8 + h * 4);
                }
    };
    auto STAGE_WRITE = [&]() {        // f32 -> fp16 + swizzled LDS write
#pragma unroll
        for (int ga = 0; ga < 2; ++ga)
#pragma unroll
            for (int q = 0; q < 4; ++q) {
                const int row = q * 32 + srow;
                const int4 hv = cvt8h(__builtin_bit_cast(float4, stg[(ga * 4 + q) * 2]),
                                      __builtin_bit_cast(float4, stg[(ga * 4 + q) * 2 + 1]));
                *reinterpret_cast<int4*>(lds + ga * 16384 + row * 128 +
                                         ((ss ^ (row & 7)) << 4)) = hv;
            }
    };
    auto CHUNKS = [&]() {             // 4 x K=16 over staged 64-k phase, single fp16 pass
#pragma unroll
        for (int c = 0; c < 4; ++c) {
            half8 ah[2], bh[2];
#pragma unroll
            for (int a = 0; a < 2; ++a) {
                const int row = Rw + a * 32 + l31;
                const int off = row * 128 + (((c * 2 + kg) ^ (row & 7)) << 4);
                ah[a] = *reinterpret_cast<const half8*>(lds + off);
            }
#pragma unroll
            for (int b = 0; b < 2; ++b) {
                const int row = Cw + b * 32 + l31;
                const int off = row * 128 + (((c * 2 + kg) ^ (row & 7)) << 4);
                bh[b] = *reinterpret_cast<const half8*>(lds + 16384 + off);
            }
#pragma unroll
            for (int a = 0; a < 2; ++a)
#pragma unroll
                for (int b = 0; b < 2; ++b)
                    acc[a][b] = __builtin_amdgcn_mfma_f32_32x32x16_f16(ah[a], bh[b], acc[a][b], 0, 0, 0);
        }
    };

    for (int ct = 0; ct < TPT; ++ct) {
        colBase = (bx * TPT + ct) * 128;
        STAGE_LOAD(0);          // regs only; safe before barrier
        __syncthreads();        // all waves done READING previous tile's LDS
        STAGE_WRITE();
        __syncthreads();        // phase-0 tiles visible
        STAGE_LOAD(1);          // issue phase-1 globals early (T14)
        CHUNKS();               // k 0..63
        __syncthreads();
        STAGE_WRITE();
        __syncthreads();        // phase-1 tiles visible
        CHUNKS();               // k 64..127

        // fused epilogue-accumulate (regs + cached scalar loads only)
        float sqJ[2]; int labJ[2], jg[2];
#pragma unroll
        for (int b = 0; b < 2; ++b) {
            jg[b]   = colBase + Cw + b * 32 + l31;
            sqJ[b]  = sqn[jg[b]];
            labJ[b] = labels[jg[b]];
        }
#pragma unroll
        for (int a = 0; a < 2; ++a)
#pragma unroll
            for (int rr = 0; rr < 16; ++rr) {
                const int crow = (rr & 3) + 8 * (rr >> 2) + 4 * kg;  // C/D map (m74/m101)
                const int ig = rowBase + Rw + a * 32 + crow;
                const float sI = sqn[ig];
                const int   lI = labels[ig];
#pragma unroll
                for (int b = 0; b < 2; ++b) {
                    const float v  = acc[a][b][rr];
                    const float d2 = fmaf(-2.0f, v, sI + sqJ[b]);
                    const bool same = (lI == labJ[b]);
                    const float pc = (same && ig != jg[b]) ? fmaxf(d2, 0.0f) : -1.0f;
                    const float nc = same ? HN_INITF : d2;
                    hpv[a][rr] = fmaxf(hpv[a][rr], pc);
                    hnv[a][rr] = fminf(hnv[a][rr], nc);
                }
            }
#pragma unroll
        for (int a = 0; a < 2; ++a)
#pragma unroll
            for (int b = 0; b < 2; ++b)
#pragma unroll
                for (int i = 0; i < 16; ++i) acc[a][b][i] = 0.0f;
    }

    __syncthreads();            // all tiles done -> LDS becomes scratch
    // per-wave [64 rows][32 cols] fold (R13-verified)
    char* scr = lds + w * 16384;
#pragma unroll
    for (int a = 0; a < 2; ++a)
#pragma unroll
        for (int rr = 0; rr < 16; ++rr) {
            const int crow = (rr & 3) + 8 * (rr >> 2) + 4 * kg;
            *reinterpret_cast<float2*>(scr + ((a * 32 + crow) * 32 + l31) * 8) =
                make_float2(hpv[a][rr], hnv[a][rr]);
        }
    float hpr = -1.0f, hnr = HN_INITF;   // same-wave LDS ordering via lgkmcnt
#pragma unroll
    for (int c = 0; c < 32; ++c) {
        const int cc = (c + l31) & 31;   // rotated read -> conflict-free
        const float2 pv = *reinterpret_cast<const float2*>(scr + l * 256 + cc * 8);
        hpr = fmaxf(hpr, pv.x);
        hnr = fminf(hnr, pv.y);
    }
    // cross-wave column-half fold: waves {0,1} rows 0..63, {2,3} rows 64..127
    __syncthreads();
    float2* xw = reinterpret_cast<float2*>(lds);   // [4][64]
    xw[w * 64 + l] = make_float2(hpr, hnr);
    __syncthreads();
    if (t < 128) {
        const int r  = t;
        const int wa = (r < 64) ? 0 : 2;
        const int li = r & 63;
        const float2 u0 = xw[wa * 64 + li];
        const float2 u1 = xw[(wa + 1) * 64 + li];
        const float fp = fmaxf(u0.x, u1.x);
        const float fn = fminf(u0.y, u1.y);
        const int gr = rowBase + r;
        // UNCONDITIONAL device-scope atomics (R12: load pre-check fails on replay)
        atomicMax(hp + gr, __float_as_int(fp));
        atomicMin(hn + gr, __float_as_int(fn));
    }
}

// ---------------- K3: per-row loss + mean over valid ----------------
__global__ __launch_bounds__(1024) void k3_loss(
        const int* __restrict__ hp, const int* __restrict__ hn, float* __restrict__ out) {
    __shared__ float sS[16], sC[16];
    const int t = threadIdx.x;
    float sum = 0.f, cnt = 0.f;
#pragma unroll
    for (int q = 0; q < BN / 1024; ++q) {
        const int r = t + 1024 * q;
        const float p2 = __int_as_float(hp[r]);
        const float n2 = __int_as_float(hn[r]);
        if (p2 >= 0.f && n2 < 1e29f) {
            const float dp = sqrtf(fmaxf(p2, 1e-12f));
            const float dn = sqrtf(fmaxf(n2, 1e-12f));
            sum += fmaxf(dp - dn + MARGIN, 0.f);
            cnt += 1.f;
        }
    }
#pragma unroll
    for (int off = 32; off > 0; off >>= 1) {
        sum += __shfl_down(sum, off);
        cnt += __shfl_down(cnt, off);
    }
    const int wv = t >> 6;
    if ((t & 63) == 0) { sS[wv] = sum; sC[wv] = cnt; }
    __syncthreads();
    if (t == 0) {
        float S = 0.f, C = 0.f;
#pragma unroll
        for (int q = 0; q < 16; ++q) { S += sS[q]; C += sC[q]; }
        out[0] = S / fmaxf(C, 1.f);
    }
}

extern "C" void kernel_launch(void* const* d_in, const int* in_sizes, int n_in,
                              void* d_out, int out_size, void* d_ws, size_t ws_size,
                              hipStream_t stream) {
    const float* emb    = (const float*)d_in[0];
    const int*   labels = (const int*)d_in[1];
    char* ws = (char*)d_ws;
    float* out = (float*)d_out;

    // 48 KB footprint (proven safe across R7/R11/R13)
    float* sqn = (float*)ws;
    int*   hp  = (int*)(ws + 16384);
    int*   hn  = (int*)(ws + 32768);

    k1_prep<<<BN / 4, 256, 0, stream>>>(emb, sqn, hp, hn);
    k2_pairs<<<512, 256, 0, stream>>>(emb, sqn, labels, hp, hn);
    k3_loss<<<1, 1024, 0, stream>>>(hp, hn, out);
}